// Round 3
// baseline (567.351 us; speedup 1.0000x reference)
//
#include <hip/hip_runtime.h>
#include <math.h>

// AdaBoost fused inference, LDS-free MFMA GEMM:
//   logits = x @ W^T + b   [N=131072, E=256], F=512; pred = (logit > 0)
//   out = sign( sum_e trunc(alpha_e) * pred_e ); only cols with trunc(alpha)!=0 matter.
//
// fp32 -> bf16 split: v = hi + lo (both RNE bf16). logit ~= xh*wh + xl*wh + xh*wl
// (xl*wl dropped; |err| << TAU). Borderline |logit| < TAU re-decided in exact fp64.
//
// Structure: prep kernel (1 block) compacts active estimators and pre-converts
// their W rows to bf16 hi/lo in d_ws. Main kernel: each wave owns 32 rows,
// loads A-frags straight from global fp32 x (contiguous 8-float runs per lane,
// converted in registers) and B-frags straight from the pre-converted bf16 W.
// NO LDS / NO barriers in the K-loop -> latency hidden by 12-16 waves/CU.

#define F_DIM 512
#define E_DIM 256
#define BMROWS 128     // rows per block (4 waves x 32)
#define CPP    96      // compacted cols per pass
#define NTMAX  6       // 16-col MFMA tiles per pass
#define NSLOT  288     // padded compacted-col slots (covers E=256)
#define TAU    1e-3f

typedef float f32x4  __attribute__((ext_vector_type(4)));
typedef short bf16x8 __attribute__((ext_vector_type(8)));

__device__ inline unsigned short bf16_rne(float v) {
    unsigned u = __float_as_uint(v);
    u += 0x7FFFu + ((u >> 16) & 1u);
    return (unsigned short)(u >> 16);
}
__device__ inline float bf16_to_f32(unsigned short h) {
    return __uint_as_float(((unsigned)h) << 16);
}
__device__ inline void cvt8(const float4& a, const float4& b, bf16x8& h8, bf16x8& l8) {
    const float v[8] = {a.x, a.y, a.z, a.w, b.x, b.y, b.z, b.w};
    #pragma unroll
    for (int j = 0; j < 8; ++j) {
        const unsigned short h = bf16_rne(v[j]);
        h8[j] = (short)h;
        l8[j] = (short)bf16_rne(v[j] - bf16_to_f32(h));
    }
}

__device__ __attribute__((noinline)) bool exact_pred(const float* __restrict__ xr,
                                                     const float* __restrict__ wr,
                                                     float bv) {
    double s0 = 0.0, s1 = 0.0, s2 = 0.0, s3 = 0.0;
    for (int k = 0; k < F_DIM; k += 4) {
        s0 = fma((double)xr[k + 0], (double)wr[k + 0], s0);
        s1 = fma((double)xr[k + 1], (double)wr[k + 1], s1);
        s2 = fma((double)xr[k + 2], (double)wr[k + 2], s2);
        s3 = fma((double)xr[k + 3], (double)wr[k + 3], s3);
    }
    double s = ((s0 + s1) + (s2 + s3)) + (double)bv;
    return s > 0.0;
}

// ---- prep: compact active estimators, convert their W rows to bf16 hi/lo ----
__global__ __launch_bounds__(1024)
void ada_prep(const float* __restrict__ W, const float* __restrict__ alphas,
              unsigned short* __restrict__ whi, unsigned short* __restrict__ wlo) {
    __shared__ int se[NSLOT];
    __shared__ int wcnt[16];

    const int tid = threadIdx.x;
    if (tid < NSLOT) se[tid] = -1;          // -1 => zero-fill row
    if (tid < 16) wcnt[tid] = 0;
    __syncthreads();

    const bool in_e = (tid < E_DIM);
    const float t = in_e ? truncf(alphas[tid]) : 0.0f;
    const bool flag = in_e && (t != 0.0f);
    const unsigned long long m64 = __ballot(flag);
    const int lane = tid & 63, wvi = tid >> 6;
    if (lane == 0) wcnt[wvi] = __popcll(m64);
    __syncthreads();
    if (flag) {
        int off = 0;
        #pragma unroll
        for (int w = 0; w < 4; ++w) if (w < wvi) off += wcnt[w];
        se[off + __popcll(m64 & ((1ull << lane) - 1ull))] = tid;
    }
    __syncthreads();

    // convert: NSLOT rows x 512 floats, float2 granules, coalesced per row
    for (int p = tid; p < NSLOT * (F_DIM / 2); p += 1024) {
        const int row = p >> 8;              // F_DIM/2 == 256
        const int cp  = (p & 255) * 2;
        const int e   = se[row];
        float2 v = make_float2(0.0f, 0.0f);
        if (e >= 0) v = *(const float2*)(W + (size_t)e * F_DIM + cp);
        ushort2 h2, l2;
        h2.x = bf16_rne(v.x); l2.x = bf16_rne(v.x - bf16_to_f32(h2.x));
        h2.y = bf16_rne(v.y); l2.y = bf16_rne(v.y - bf16_to_f32(h2.y));
        *(ushort2*)(whi + (size_t)row * F_DIM + cp) = h2;
        *(ushort2*)(wlo + (size_t)row * F_DIM + cp) = l2;
    }
}

// ---- main GEMM: LDS-free, barrier-free K-loop ----
template<bool PREW>
__global__ __launch_bounds__(256)
void ada_gemm(const float* __restrict__ x, const float* __restrict__ W,
              const float* __restrict__ bias, const float* __restrict__ alphas,
              const unsigned short* __restrict__ whi,
              const unsigned short* __restrict__ wlo,
              float* __restrict__ out) {
    __shared__ int   se[NSLOT];
    __shared__ float st[NSLOT];
    __shared__ float sb[NSLOT];
    __shared__ int   wcnt[4];

    const int tid = threadIdx.x;

    // ---- per-block compaction (deterministic, matches prep's ordering)
    se[tid] = 0; st[tid] = 0.0f; sb[tid] = 0.0f;
    if (tid < NSLOT - E_DIM) { se[E_DIM + tid] = 0; st[E_DIM + tid] = 0.0f; sb[E_DIM + tid] = 0.0f; }
    __syncthreads();
    const float t = truncf(alphas[tid]);
    const bool flag = (t != 0.0f);
    const unsigned long long m64 = __ballot(flag);
    const int lane = tid & 63, wvi = tid >> 6;
    if (lane == 0) wcnt[wvi] = __popcll(m64);
    __syncthreads();
    const int M = wcnt[0] + wcnt[1] + wcnt[2] + wcnt[3];
    if (flag) {
        int off = 0;
        #pragma unroll
        for (int w = 0; w < 4; ++w) if (w < wvi) off += wcnt[w];
        const int slot = off + __popcll(m64 & ((1ull << lane) - 1ull));
        se[slot] = tid; st[slot] = t; sb[slot] = bias[tid];
    }
    __syncthreads();   // the only block-wide barrier before the epilogue

    const int l15  = tid & 15;
    const int quad = (tid >> 4) & 3;
    const int wave = tid >> 6;
    const int rowbase = blockIdx.x * BMROWS + wave * 32;   // + mt*16 + ...
    const float* xrow = x + (size_t)(rowbase + l15) * F_DIM + quad * 8;

    int part[2][4];
    #pragma unroll
    for (int mt = 0; mt < 2; ++mt)
        #pragma unroll
        for (int r = 0; r < 4; ++r) part[mt][r] = 0;

    for (int cb = 0; cb < M; cb += CPP) {
        const int Mrem = M - cb;
        const int NT = ((Mrem + 15) >> 4) < NTMAX ? ((Mrem + 15) >> 4) : NTMAX;

        f32x4 acc[2][NTMAX];
        #pragma unroll
        for (int mt = 0; mt < 2; ++mt)
            #pragma unroll
            for (int nt = 0; nt < NTMAX; ++nt)
                acc[mt][nt] = (f32x4){0.0f, 0.0f, 0.0f, 0.0f};

        const unsigned short* bhp[NTMAX];
        const unsigned short* blp[NTMAX];
        const float* wrp[NTMAX];
        #pragma unroll
        for (int nt = 0; nt < NTMAX; ++nt) {
            const int col = cb + nt * 16 + l15;       // < NSLOT by construction
            if (PREW) {
                bhp[nt] = whi + (size_t)col * F_DIM + quad * 8;
                blp[nt] = wlo + (size_t)col * F_DIM + quad * 8;
            } else {
                wrp[nt] = W + (size_t)se[col] * F_DIM + quad * 8;
            }
        }

        // register double-buffer for the x A-frags (HBM stream)
        float4 xc0[2], xc1[2];
        #pragma unroll
        for (int mt = 0; mt < 2; ++mt) {
            const float* p = xrow + (size_t)mt * 16 * F_DIM;
            xc0[mt] = *(const float4*)(p);
            xc1[mt] = *(const float4*)(p + 4);
        }

        for (int k0 = 0; k0 < F_DIM; k0 += 32) {
            float4 xn0[2], xn1[2];
            const bool more = (k0 + 32) < F_DIM;
            if (more) {
                #pragma unroll
                for (int mt = 0; mt < 2; ++mt) {
                    const float* p = xrow + (size_t)mt * 16 * F_DIM + k0 + 32;
                    xn0[mt] = *(const float4*)(p);
                    xn1[mt] = *(const float4*)(p + 4);
                }
            }

            bf16x8 ah[2], al[2];
            #pragma unroll
            for (int mt = 0; mt < 2; ++mt)
                cvt8(xc0[mt], xc1[mt], ah[mt], al[mt]);

            #pragma unroll
            for (int nt = 0; nt < NTMAX; ++nt) {
                if (nt < NT) {
                    bf16x8 bh, bl;
                    if (PREW) {
                        bh = *(const bf16x8*)(bhp[nt] + k0);
                        bl = *(const bf16x8*)(blp[nt] + k0);
                    } else {
                        const float4 wa = *(const float4*)(wrp[nt] + k0);
                        const float4 wb = *(const float4*)(wrp[nt] + k0 + 4);
                        cvt8(wa, wb, bh, bl);
                    }
                    #pragma unroll
                    for (int mt = 0; mt < 2; ++mt) {
                        acc[mt][nt] = __builtin_amdgcn_mfma_f32_16x16x32_bf16(ah[mt], bh, acc[mt][nt], 0, 0, 0);
                        acc[mt][nt] = __builtin_amdgcn_mfma_f32_16x16x32_bf16(al[mt], bh, acc[mt][nt], 0, 0, 0);
                        acc[mt][nt] = __builtin_amdgcn_mfma_f32_16x16x32_bf16(ah[mt], bl, acc[mt][nt], 0, 0, 0);
                    }
                }
            }

            if (more) {
                #pragma unroll
                for (int mt = 0; mt < 2; ++mt) { xc0[mt] = xn0[mt]; xc1[mt] = xn1[mt]; }
            }
        }

        // ---- epilogue for this pass: threshold + integer vote
        // C/D layout: col = l15 (within 16-tile), row = quad*4 + reg
        #pragma unroll
        for (int nt = 0; nt < NTMAX; ++nt) {
            if (nt < NT) {
                const int col = cb + nt * 16 + l15;
                const float tv = st[col];
                if (tv != 0.0f) {
                    const float bv = sb[col];
                    const int it = (int)tv;
                    #pragma unroll
                    for (int mt = 0; mt < 2; ++mt) {
                        #pragma unroll
                        for (int r = 0; r < 4; ++r) {
                            const float logit = acc[mt][nt][r] + bv;
                            bool pred = (logit > 0.0f);
                            if (fabsf(logit) < TAU) {
                                const int grow = rowbase + mt * 16 + quad * 4 + r;
                                pred = exact_pred(x + (size_t)grow * F_DIM,
                                                  W + (size_t)se[col] * F_DIM, bv);
                            }
                            if (pred) part[mt][r] += it;
                        }
                    }
                }
            }
        }
    }

    // ---- reduce votes across the 16 col-lanes, store 4 rows as float4
    #pragma unroll
    for (int mt = 0; mt < 2; ++mt) {
        #pragma unroll
        for (int r = 0; r < 4; ++r) {
            int v = part[mt][r];
            v += __shfl_xor(v, 1);
            v += __shfl_xor(v, 2);
            v += __shfl_xor(v, 4);
            v += __shfl_xor(v, 8);
            part[mt][r] = v;
        }
    }
    if (l15 == 0) {
        #pragma unroll
        for (int mt = 0; mt < 2; ++mt) {
            float4 o;
            o.x = (part[mt][0] > 0) ? 1.0f : (part[mt][0] < 0 ? -1.0f : 0.0f);
            o.y = (part[mt][1] > 0) ? 1.0f : (part[mt][1] < 0 ? -1.0f : 0.0f);
            o.z = (part[mt][2] > 0) ? 1.0f : (part[mt][2] < 0 ? -1.0f : 0.0f);
            o.w = (part[mt][3] > 0) ? 1.0f : (part[mt][3] < 0 ? -1.0f : 0.0f);
            *(float4*)(out + rowbase + mt * 16 + quad * 4) = o;
        }
    }
}

extern "C" void kernel_launch(void* const* d_in, const int* in_sizes, int n_in,
                              void* d_out, int out_size, void* d_ws, size_t ws_size,
                              hipStream_t stream) {
    const float* x      = (const float*)d_in[0];   // [N, 512]
    const float* W      = (const float*)d_in[1];   // [256, 512]
    const float* bias   = (const float*)d_in[2];   // [256]
    const float* alphas = (const float*)d_in[3];   // [256]
    float* out = (float*)d_out;                    // [N]

    const int n = in_sizes[0] / F_DIM;             // 131072
    const int nblocks = n / BMROWS;                // 1024

    const size_t wsneed = (size_t)NSLOT * F_DIM * 2 * sizeof(unsigned short);
    if (ws_size >= wsneed) {
        unsigned short* whi = (unsigned short*)d_ws;
        unsigned short* wlo = whi + (size_t)NSLOT * F_DIM;
        ada_prep<<<dim3(1), dim3(1024), 0, stream>>>(W, alphas, whi, wlo);
        ada_gemm<true><<<dim3(nblocks), dim3(256), 0, stream>>>(x, W, bias, alphas, whi, wlo, out);
    } else {
        ada_gemm<false><<<dim3(nblocks), dim3(256), 0, stream>>>(x, W, bias, alphas, nullptr, nullptr, out);
    }
}

// Round 4
// 517.652 us; speedup vs baseline: 1.0960x; 1.0960x over previous
//
#include <hip/hip_runtime.h>
#include <math.h>

// AdaBoost fused inference, LDS-free MFMA GEMM with CALL-FREE hot loop.
//   logits = x @ W^T + b   [N=131072, E=256], F=512; pred = (logit > 0)
//   out = sign( sum_e trunc(alpha_e) * pred_e ); only cols with trunc(alpha)!=0 matter.
//
// fp32 -> bf16 split: v = hi + lo (RNE). logit ~= xh*wh + xl*wh + xh*wl
// (|err| < ~2.5e-4 << TAU). Borderline |logit| < TAU entries are APPENDED to a
// fixup list (no fp64, no calls in the GEMM kernel -> no scratch -> full
// occupancy); a small second kernel decides them with the exact fp64 dot and
// atomically adjusts the votes; a third kernel converts votes -> sign.

#define F_DIM 512
#define E_DIM 256
#define BMROWS 128     // rows per block (4 waves x 32)
#define CPP    96      // compacted cols per pass
#define NTMAX  6       // 16-col MFMA tiles per pass
#define NSLOT  288     // padded compacted-col slots (covers E=256)
#define TAU    1e-3f

typedef float f32x4  __attribute__((ext_vector_type(4)));
typedef short bf16x8 __attribute__((ext_vector_type(8)));

__device__ __forceinline__ unsigned short bf16_rne(float v) {
    unsigned u = __float_as_uint(v);
    u += 0x7FFFu + ((u >> 16) & 1u);
    return (unsigned short)(u >> 16);
}
__device__ __forceinline__ float bf16_to_f32(unsigned short h) {
    return __uint_as_float(((unsigned)h) << 16);
}
__device__ __forceinline__ void cvt8(const float4& a, const float4& b, bf16x8& h8, bf16x8& l8) {
    const float v[8] = {a.x, a.y, a.z, a.w, b.x, b.y, b.z, b.w};
    #pragma unroll
    for (int j = 0; j < 8; ++j) {
        const unsigned short h = bf16_rne(v[j]);
        h8[j] = (short)h;
        l8[j] = (short)bf16_rne(v[j] - bf16_to_f32(h));
    }
}

// Exact decision — MUST stay bit-identical to the method that passed rounds 1-3.
__device__ __forceinline__ bool exact_pred(const float* __restrict__ xr,
                                           const float* __restrict__ wr,
                                           float bv) {
    double s0 = 0.0, s1 = 0.0, s2 = 0.0, s3 = 0.0;
    for (int k = 0; k < F_DIM; k += 4) {
        s0 = fma((double)xr[k + 0], (double)wr[k + 0], s0);
        s1 = fma((double)xr[k + 1], (double)wr[k + 1], s1);
        s2 = fma((double)xr[k + 2], (double)wr[k + 2], s2);
        s3 = fma((double)xr[k + 3], (double)wr[k + 3], s3);
    }
    double s = ((s0 + s1) + (s2 + s3)) + (double)bv;
    return s > 0.0;
}

// ---- prep: one block per compacted slot; convert W row to bf16 hi/lo -------
__global__ __launch_bounds__(256)
void ada_prep(const float* __restrict__ W, const float* __restrict__ alphas,
              unsigned short* __restrict__ whi, unsigned short* __restrict__ wlo,
              int* __restrict__ counter) {
    __shared__ int wcnt[4];
    __shared__ int slot_e;

    const int tid  = threadIdx.x;
    const int slot = blockIdx.x;
    if (slot == 0 && tid == 0) *counter = 0;

    const float t = truncf(alphas[tid]);
    const bool flag = (t != 0.0f);
    const unsigned long long m64 = __ballot(flag);
    const int lane = tid & 63, wvi = tid >> 6;
    if (lane == 0) wcnt[wvi] = __popcll(m64);
    if (tid == 0) slot_e = -1;
    __syncthreads();
    if (flag) {
        int off = 0;
        #pragma unroll
        for (int w = 0; w < 4; ++w) if (w < wvi) off += wcnt[w];
        if (off + __popcll(m64 & ((1ull << lane) - 1ull)) == slot) slot_e = tid;
    }
    __syncthreads();

    const int e = slot_e;
    const int cp = tid * 2;
    float2 v = make_float2(0.0f, 0.0f);
    if (e >= 0) v = *(const float2*)(W + (size_t)e * F_DIM + cp);
    ushort2 h2, l2;
    h2.x = bf16_rne(v.x); l2.x = bf16_rne(v.x - bf16_to_f32(h2.x));
    h2.y = bf16_rne(v.y); l2.y = bf16_rne(v.y - bf16_to_f32(h2.y));
    *(ushort2*)(whi + (size_t)slot * F_DIM + cp) = h2;
    *(ushort2*)(wlo + (size_t)slot * F_DIM + cp) = l2;
}

// ---- main GEMM: LDS-free, barrier-free, CALL-FREE K-loop -------------------
__global__ __launch_bounds__(256)
void ada_gemm(const float* __restrict__ x,
              const float* __restrict__ alphas, const float* __restrict__ bias,
              const unsigned short* __restrict__ whi,
              const unsigned short* __restrict__ wlo,
              int* __restrict__ counter, int2* __restrict__ list, int cap,
              float* __restrict__ out) {
    __shared__ int   se[NSLOT];
    __shared__ float st[NSLOT];
    __shared__ float sb[NSLOT];
    __shared__ int   wcnt[4];

    const int tid = threadIdx.x;

    // per-block compaction (deterministic; matches prep ordering)
    se[tid] = 0; st[tid] = 0.0f; sb[tid] = 0.0f;
    if (tid < NSLOT - E_DIM) { se[E_DIM + tid] = 0; st[E_DIM + tid] = 0.0f; sb[E_DIM + tid] = 0.0f; }
    __syncthreads();
    const float t = truncf(alphas[tid]);
    const bool flag = (t != 0.0f);
    const unsigned long long m64 = __ballot(flag);
    const int lane = tid & 63, wvi = tid >> 6;
    if (lane == 0) wcnt[wvi] = __popcll(m64);
    __syncthreads();
    const int M = wcnt[0] + wcnt[1] + wcnt[2] + wcnt[3];
    if (flag) {
        int off = 0;
        #pragma unroll
        for (int w = 0; w < 4; ++w) if (w < wvi) off += wcnt[w];
        const int slot = off + __popcll(m64 & ((1ull << lane) - 1ull));
        se[slot] = tid; st[slot] = t; sb[slot] = bias[tid];
    }
    __syncthreads();

    const int l15  = tid & 15;
    const int quad = (tid >> 4) & 3;
    const int wave = tid >> 6;
    const int rowbase = blockIdx.x * BMROWS + wave * 32;
    const float* xrow = x + (size_t)(rowbase + l15) * F_DIM + quad * 8;

    int part[2][4];
    #pragma unroll
    for (int mt = 0; mt < 2; ++mt)
        #pragma unroll
        for (int r = 0; r < 4; ++r) part[mt][r] = 0;

    for (int cb = 0; cb < M; cb += CPP) {
        const int Mrem = M - cb;
        const int NT = ((Mrem + 15) >> 4) < NTMAX ? ((Mrem + 15) >> 4) : NTMAX;

        f32x4 acc[2][NTMAX];
        #pragma unroll
        for (int mt = 0; mt < 2; ++mt)
            #pragma unroll
            for (int nt = 0; nt < NTMAX; ++nt)
                acc[mt][nt] = (f32x4){0.0f, 0.0f, 0.0f, 0.0f};

        const unsigned short* bhp[NTMAX];
        const unsigned short* blp[NTMAX];
        #pragma unroll
        for (int nt = 0; nt < NTMAX; ++nt) {
            const int col = cb + nt * 16 + l15;     // < NSLOT by construction
            bhp[nt] = whi + (size_t)col * F_DIM + quad * 8;
            blp[nt] = wlo + (size_t)col * F_DIM + quad * 8;
        }

        // register double-buffer for the x A-frags (HBM stream)
        float4 xc0[2], xc1[2];
        #pragma unroll
        for (int mt = 0; mt < 2; ++mt) {
            const float* p = xrow + (size_t)mt * 16 * F_DIM;
            xc0[mt] = *(const float4*)(p);
            xc1[mt] = *(const float4*)(p + 4);
        }

        for (int k0 = 0; k0 < F_DIM; k0 += 32) {
            float4 xn0[2], xn1[2];
            const bool more = (k0 + 32) < F_DIM;
            if (more) {
                #pragma unroll
                for (int mt = 0; mt < 2; ++mt) {
                    const float* p = xrow + (size_t)mt * 16 * F_DIM + k0 + 32;
                    xn0[mt] = *(const float4*)(p);
                    xn1[mt] = *(const float4*)(p + 4);
                }
            }

            bf16x8 ah[2], al[2];
            #pragma unroll
            for (int mt = 0; mt < 2; ++mt)
                cvt8(xc0[mt], xc1[mt], ah[mt], al[mt]);

            #pragma unroll
            for (int nt = 0; nt < NTMAX; ++nt) {
                if (nt < NT) {
                    const bf16x8 bh = *(const bf16x8*)(bhp[nt] + k0);
                    const bf16x8 bl = *(const bf16x8*)(blp[nt] + k0);
                    #pragma unroll
                    for (int mt = 0; mt < 2; ++mt) {
                        acc[mt][nt] = __builtin_amdgcn_mfma_f32_16x16x32_bf16(ah[mt], bh, acc[mt][nt], 0, 0, 0);
                        acc[mt][nt] = __builtin_amdgcn_mfma_f32_16x16x32_bf16(al[mt], bh, acc[mt][nt], 0, 0, 0);
                        acc[mt][nt] = __builtin_amdgcn_mfma_f32_16x16x32_bf16(ah[mt], bl, acc[mt][nt], 0, 0, 0);
                    }
                }
            }

            if (more) {
                #pragma unroll
                for (int mt = 0; mt < 2; ++mt) { xc0[mt] = xn0[mt]; xc1[mt] = xn1[mt]; }
            }
        }

        // epilogue: threshold + integer vote; borderline -> fixup list (no fp64 here)
        // C/D layout: col = l15 (within 16-tile), row = quad*4 + reg
        #pragma unroll
        for (int nt = 0; nt < NTMAX; ++nt) {
            if (nt < NT) {
                const int col = cb + nt * 16 + l15;
                const float tv = st[col];
                if (tv != 0.0f) {
                    const float bv = sb[col];
                    const int it = (int)tv;
                    #pragma unroll
                    for (int mt = 0; mt < 2; ++mt) {
                        #pragma unroll
                        for (int r = 0; r < 4; ++r) {
                            const float logit = acc[mt][nt][r] + bv;
                            if (fabsf(logit) >= TAU) {
                                if (logit > 0.0f) part[mt][r] += it;
                            } else {
                                const int grow = rowbase + mt * 16 + quad * 4 + r;
                                const int idx = atomicAdd(counter, 1);
                                if (idx < cap) {
                                    list[idx] = make_int2(grow, se[col] | (it << 16));
                                } else if (logit > 0.0f) {
                                    part[mt][r] += it;   // overflow: best-effort fp32
                                }
                            }
                        }
                    }
                }
            }
        }
    }

    // reduce votes across the 16 col-lanes, store raw votes (float) per row
    #pragma unroll
    for (int mt = 0; mt < 2; ++mt) {
        #pragma unroll
        for (int r = 0; r < 4; ++r) {
            int v = part[mt][r];
            v += __shfl_xor(v, 1);
            v += __shfl_xor(v, 2);
            v += __shfl_xor(v, 4);
            v += __shfl_xor(v, 8);
            part[mt][r] = v;
        }
    }
    if (l15 == 0) {
        #pragma unroll
        for (int mt = 0; mt < 2; ++mt) {
            float4 o;
            o.x = (float)part[mt][0];
            o.y = (float)part[mt][1];
            o.z = (float)part[mt][2];
            o.w = (float)part[mt][3];
            *(float4*)(out + rowbase + mt * 16 + quad * 4) = o;
        }
    }
}

// ---- fixup: exact fp64 decision for the borderline entries -----------------
__global__ __launch_bounds__(256)
void ada_fixup(const float* __restrict__ x, const float* __restrict__ W,
               const float* __restrict__ bias,
               const int* __restrict__ counter, const int2* __restrict__ list,
               int cap, float* __restrict__ out) {
    int n = *counter;
    if (n > cap) n = cap;
    const int stride = gridDim.x * blockDim.x;
    for (int i = blockIdx.x * blockDim.x + threadIdx.x; i < n; i += stride) {
        const int2 ent = list[i];
        const int row = ent.x;
        const int e   = ent.y & 0xFFFF;
        const int it  = ent.y >> 16;           // arithmetic shift recovers sign
        if (exact_pred(x + (size_t)row * F_DIM, W + (size_t)e * F_DIM, bias[e]))
            atomicAdd(out + row, (float)it);
    }
}

// ---- sign: votes -> {-1,0,1} in place --------------------------------------
__global__ __launch_bounds__(256)
void ada_sign(float* __restrict__ out) {
    const int i = (blockIdx.x * blockDim.x + threadIdx.x) * 4;
    float4 v = *(float4*)(out + i);
    v.x = (v.x > 0.0f) ? 1.0f : (v.x < 0.0f ? -1.0f : 0.0f);
    v.y = (v.y > 0.0f) ? 1.0f : (v.y < 0.0f ? -1.0f : 0.0f);
    v.z = (v.z > 0.0f) ? 1.0f : (v.z < 0.0f ? -1.0f : 0.0f);
    v.w = (v.w > 0.0f) ? 1.0f : (v.w < 0.0f ? -1.0f : 0.0f);
    *(float4*)(out + i) = v;
}

// ---- fallback (ws too small): round-3 style, self-contained ----------------
__global__ __launch_bounds__(256)
void ada_gemm_fb(const float* __restrict__ x, const float* __restrict__ W,
                 const float* __restrict__ bias, const float* __restrict__ alphas,
                 float* __restrict__ out) {
    __shared__ int   se[NSLOT];
    __shared__ float st[NSLOT];
    __shared__ float sb[NSLOT];
    __shared__ int   wcnt[4];

    const int tid = threadIdx.x;
    se[tid] = 0; st[tid] = 0.0f; sb[tid] = 0.0f;
    if (tid < NSLOT - E_DIM) { se[E_DIM + tid] = 0; st[E_DIM + tid] = 0.0f; sb[E_DIM + tid] = 0.0f; }
    __syncthreads();
    const float t = truncf(alphas[tid]);
    const bool flag = (t != 0.0f);
    const unsigned long long m64 = __ballot(flag);
    const int lane = tid & 63, wvi = tid >> 6;
    if (lane == 0) wcnt[wvi] = __popcll(m64);
    __syncthreads();
    const int M = wcnt[0] + wcnt[1] + wcnt[2] + wcnt[3];
    if (flag) {
        int off = 0;
        #pragma unroll
        for (int w = 0; w < 4; ++w) if (w < wvi) off += wcnt[w];
        const int slot = off + __popcll(m64 & ((1ull << lane) - 1ull));
        se[slot] = tid; st[slot] = t; sb[slot] = bias[tid];
    }
    __syncthreads();

    const int l15  = tid & 15;
    const int quad = (tid >> 4) & 3;
    const int wave = tid >> 6;
    const int rowbase = blockIdx.x * BMROWS + wave * 32;
    const float* xrow = x + (size_t)(rowbase + l15) * F_DIM + quad * 8;

    int part[2][4];
    #pragma unroll
    for (int mt = 0; mt < 2; ++mt)
        #pragma unroll
        for (int r = 0; r < 4; ++r) part[mt][r] = 0;

    for (int cb = 0; cb < M; cb += CPP) {
        const int Mrem = M - cb;
        const int NT = ((Mrem + 15) >> 4) < NTMAX ? ((Mrem + 15) >> 4) : NTMAX;

        f32x4 acc[2][NTMAX];
        #pragma unroll
        for (int mt = 0; mt < 2; ++mt)
            #pragma unroll
            for (int nt = 0; nt < NTMAX; ++nt)
                acc[mt][nt] = (f32x4){0.0f, 0.0f, 0.0f, 0.0f};

        const float* wrp[NTMAX];
        #pragma unroll
        for (int nt = 0; nt < NTMAX; ++nt)
            wrp[nt] = W + (size_t)se[cb + nt * 16 + l15] * F_DIM + quad * 8;

        for (int k0 = 0; k0 < F_DIM; k0 += 32) {
            bf16x8 ah[2], al[2];
            #pragma unroll
            for (int mt = 0; mt < 2; ++mt) {
                const float* p = xrow + (size_t)mt * 16 * F_DIM + k0;
                cvt8(*(const float4*)(p), *(const float4*)(p + 4), ah[mt], al[mt]);
            }
            #pragma unroll
            for (int nt = 0; nt < NTMAX; ++nt) {
                if (nt < NT) {
                    bf16x8 bh, bl;
                    cvt8(*(const float4*)(wrp[nt] + k0), *(const float4*)(wrp[nt] + k0 + 4), bh, bl);
                    #pragma unroll
                    for (int mt = 0; mt < 2; ++mt) {
                        acc[mt][nt] = __builtin_amdgcn_mfma_f32_16x16x32_bf16(ah[mt], bh, acc[mt][nt], 0, 0, 0);
                        acc[mt][nt] = __builtin_amdgcn_mfma_f32_16x16x32_bf16(al[mt], bh, acc[mt][nt], 0, 0, 0);
                        acc[mt][nt] = __builtin_amdgcn_mfma_f32_16x16x32_bf16(ah[mt], bl, acc[mt][nt], 0, 0, 0);
                    }
                }
            }
        }

        #pragma unroll
        for (int nt = 0; nt < NTMAX; ++nt) {
            if (nt < NT) {
                const int col = cb + nt * 16 + l15;
                const float tv = st[col];
                if (tv != 0.0f) {
                    const float bv = sb[col];
                    const int it = (int)tv;
                    #pragma unroll
                    for (int mt = 0; mt < 2; ++mt) {
                        #pragma unroll
                        for (int r = 0; r < 4; ++r) {
                            const float logit = acc[mt][nt][r] + bv;
                            bool pred = (logit > 0.0f);
                            if (fabsf(logit) < TAU) {
                                const int grow = rowbase + mt * 16 + quad * 4 + r;
                                pred = exact_pred(x + (size_t)grow * F_DIM,
                                                  W + (size_t)se[col] * F_DIM, bv);
                            }
                            if (pred) part[mt][r] += it;
                        }
                    }
                }
            }
        }
    }

    #pragma unroll
    for (int mt = 0; mt < 2; ++mt) {
        #pragma unroll
        for (int r = 0; r < 4; ++r) {
            int v = part[mt][r];
            v += __shfl_xor(v, 1);
            v += __shfl_xor(v, 2);
            v += __shfl_xor(v, 4);
            v += __shfl_xor(v, 8);
            part[mt][r] = v;
        }
    }
    if (l15 == 0) {
        #pragma unroll
        for (int mt = 0; mt < 2; ++mt) {
            float4 o;
            o.x = (part[mt][0] > 0) ? 1.0f : (part[mt][0] < 0 ? -1.0f : 0.0f);
            o.y = (part[mt][1] > 0) ? 1.0f : (part[mt][1] < 0 ? -1.0f : 0.0f);
            o.z = (part[mt][2] > 0) ? 1.0f : (part[mt][2] < 0 ? -1.0f : 0.0f);
            o.w = (part[mt][3] > 0) ? 1.0f : (part[mt][3] < 0 ? -1.0f : 0.0f);
            *(float4*)(out + rowbase + mt * 16 + quad * 4) = o;
        }
    }
}

extern "C" void kernel_launch(void* const* d_in, const int* in_sizes, int n_in,
                              void* d_out, int out_size, void* d_ws, size_t ws_size,
                              hipStream_t stream) {
    const float* x      = (const float*)d_in[0];   // [N, 512]
    const float* W      = (const float*)d_in[1];   // [256, 512]
    const float* bias   = (const float*)d_in[2];   // [256]
    const float* alphas = (const float*)d_in[3];   // [256]
    float* out = (float*)d_out;                    // [N]

    const int n = in_sizes[0] / F_DIM;             // 131072
    const int nblocks = n / BMROWS;                // 1024

    const size_t whl_bytes = (size_t)NSLOT * F_DIM * sizeof(unsigned short); // 294912
    const size_t fixed     = 64 + 2 * whl_bytes;                             // 589888
    const long long cap_ll = ((long long)ws_size - (long long)fixed) / (long long)sizeof(int2);

    if (cap_ll >= 4096) {
        char* p = (char*)d_ws;
        int*            counter = (int*)p;
        unsigned short* whi     = (unsigned short*)(p + 64);
        unsigned short* wlo     = (unsigned short*)(p + 64 + whl_bytes);
        int2*           list    = (int2*)(p + fixed);
        const int cap = (int)(cap_ll > 2000000 ? 2000000 : cap_ll);

        ada_prep<<<dim3(NSLOT), dim3(256), 0, stream>>>(W, alphas, whi, wlo, counter);
        ada_gemm<<<dim3(nblocks), dim3(256), 0, stream>>>(x, alphas, bias, whi, wlo,
                                                          counter, list, cap, out);
        ada_fixup<<<dim3(64), dim3(256), 0, stream>>>(x, W, bias, counter, list, cap, out);
        ada_sign<<<dim3(n / 1024), dim3(256), 0, stream>>>(out);
    } else {
        ada_gemm_fb<<<dim3(nblocks), dim3(256), 0, stream>>>(x, W, bias, alphas, out);
    }
}